// Round 1
// baseline (471.729 us; speedup 1.0000x reference)
//
#include <hip/hip_runtime.h>
#include <math.h>

#define NROWS   8192
#define DHH     64
#define BHCOUNT 64
#define HCOUNT  16
#define SPLITA  16
#define CHUNKA  (NROWS / SPLITA)   // 512
#define GA      32                 // rows staged per LDS group in phase A
#define LSTR    68                 // padded LDS row stride (floats)
#define SPLITB  32
#define CHUNKB  (NROWS / SPLITB)   // 256
#define CTXSZ   4160               // 64*64 context + 64 v2_sum
#define EPS_DN  1e-5f
#define PROJ_EPS 0.004f

__device__ __forceinline__ float elu1(float x) {
    // elu(x)+1 : x>0 ? x+1 : exp(x)
    return x > 0.0f ? x + 1.0f : expf(x);
}

// ---------------- Phase A: per-row v2/x, accumulate context & v2_sum ----------------
__global__ __launch_bounds__(256) void phaseA(
        const float* __restrict__ Kp, const float* __restrict__ Vp,
        const float* __restrict__ maskp, const float* __restrict__ curvp,
        float* __restrict__ denomWs, float* __restrict__ partials) {
    __shared__ __align__(16) float v2s[GA * LSTR];
    __shared__ __align__(16) float xs[GA * LSTR];
    const int bx = blockIdx.x;
    const int bh = bx / SPLITA, sp = bx % SPLITA;
    const float k = curvp[bh % HCOUNT];
    const int t = threadIdx.x;
    const int rowBase = sp * CHUNKA;
    const float* Kb = Kp + (size_t)bh * NROWS * DHH;
    const float* Vb = Vp + (size_t)bh * NROWS * DHH;

    float acc[4][4] = {{0.f,0.f,0.f,0.f},{0.f,0.f,0.f,0.f},{0.f,0.f,0.f,0.f},{0.f,0.f,0.f,0.f}};
    float4 v2sum4 = make_float4(0.f, 0.f, 0.f, 0.f);
    const int rloc = t >> 4;   // 0..15
    const int c4   = t & 15;   // 0..15 (column group of 4)
    const int td   = t >> 4;   // d-tile for accumulation
    const int te   = t & 15;   // e-tile for accumulation

    for (int g = 0; g < CHUNKA / GA; ++g) {
        // ---- stage GA rows: compute v2 and x into LDS ----
        #pragma unroll
        for (int pass = 0; pass < 2; ++pass) {
            const int rl = pass * 16 + rloc;
            const int n = rowBase + g * GA + rl;
            const float4 v4 = *(const float4*)(Vb + (size_t)n * DHH + 4 * c4);
            const float4 k4 = *(const float4*)(Kb + (size_t)n * DHH + 4 * c4);
            float ss = v4.x*v4.x + v4.y*v4.y + v4.z*v4.z + v4.w*v4.w;
            ss += __shfl_xor(ss, 1);
            ss += __shfl_xor(ss, 2);
            ss += __shfl_xor(ss, 4);
            ss += __shfl_xor(ss, 8);
            const float dv    = fmaxf(1.0f + k * ss, 1e-15f);
            const float gamma = 2.0f / dv;
            const float gm1   = gamma - 1.0f;
            const float dnm   = (gm1 >= 0.0f ? 1.0f : -1.0f) * fmaxf(fabsf(gm1), 1e-10f);
            const float m     = maskp[n];
            const float idv   = 1.0f / dv;
            const float cv2   = dnm * m;
            const float cx    = (gamma / dnm) * m;
            float4 v2v, xv;
            v2v.x = cv2 * elu1(k4.x * idv);
            v2v.y = cv2 * elu1(k4.y * idv);
            v2v.z = cv2 * elu1(k4.z * idv);
            v2v.w = cv2 * elu1(k4.w * idv);
            xv.x = cx * v4.x; xv.y = cx * v4.y; xv.z = cx * v4.z; xv.w = cx * v4.w;
            *(float4*)&v2s[rl * LSTR + 4 * c4] = v2v;
            *(float4*)&xs [rl * LSTR + 4 * c4] = xv;
            v2sum4.x += v2v.x; v2sum4.y += v2v.y; v2sum4.z += v2v.z; v2sum4.w += v2v.w;
            if (c4 == 0) denomWs[(size_t)bh * NROWS + n] = dv;
        }
        __syncthreads();
        // ---- accumulate context[d0..d0+3][e0..e0+3] over GA rows ----
        #pragma unroll 4
        for (int r = 0; r < GA; ++r) {
            const float4 a = *(const float4*)&v2s[r * LSTR + 4 * td];
            const float4 b = *(const float4*)&xs [r * LSTR + 4 * te];
            acc[0][0] += a.x*b.x; acc[0][1] += a.x*b.y; acc[0][2] += a.x*b.z; acc[0][3] += a.x*b.w;
            acc[1][0] += a.y*b.x; acc[1][1] += a.y*b.y; acc[1][2] += a.y*b.z; acc[1][3] += a.y*b.w;
            acc[2][0] += a.z*b.x; acc[2][1] += a.z*b.y; acc[2][2] += a.z*b.z; acc[2][3] += a.z*b.w;
            acc[3][0] += a.w*b.x; acc[3][1] += a.w*b.y; acc[3][2] += a.w*b.z; acc[3][3] += a.w*b.w;
        }
        __syncthreads();
    }

    // ---- write partial context ----
    float* pbase = partials + (size_t)(bh * SPLITA + sp) * CTXSZ;
    #pragma unroll
    for (int i = 0; i < 4; ++i) {
        float4 o = make_float4(acc[i][0], acc[i][1], acc[i][2], acc[i][3]);
        *(float4*)(pbase + (4 * td + i) * DHH + 4 * te) = o;
    }
    // ---- reduce v2_sum across threads (reuse v2s as scratch) ----
    __syncthreads();
    *(float4*)&v2s[t * 4] = v2sum4;
    __syncthreads();
    if (t < DHH) {
        const int cc = t >> 2, j = t & 3;
        float s = 0.f;
        #pragma unroll
        for (int q = 0; q < 16; ++q) s += v2s[(q * 16 + cc) * 4 + j];
        pbase[4096 + t] = s;
    }
}

// ---------------- Reduce partials across SPLITA ----------------
__global__ __launch_bounds__(256) void reduceCtx(
        const float* __restrict__ partials, float* __restrict__ ctxsum) {
    const int bh = blockIdx.x;
    const int t = threadIdx.x;
    for (int idx = t; idx < CTXSZ; idx += 256) {
        const float* p = partials + (size_t)bh * SPLITA * CTXSZ + idx;
        float s = 0.f;
        #pragma unroll
        for (int sp = 0; sp < SPLITA; ++sp) s += p[(size_t)sp * CTXSZ];
        ctxsum[(size_t)bh * CTXSZ + idx] = s;
    }
}

// ---------------- Phase B: X = D_inv * v1 @ context, then project/mobius/project ----------------
__global__ __launch_bounds__(256) void phaseB(
        const float* __restrict__ Qp, const float* __restrict__ curvp,
        const float* __restrict__ denomWs, const float* __restrict__ ctxsum,
        float* __restrict__ outp) {
    __shared__ __align__(16) float ctx[DHH * LSTR];
    __shared__ __align__(16) float v1s[64 * LSTR];
    __shared__ __align__(16) float v2sum[DHH];
    __shared__ float dinv[64];
    __shared__ float rowsq[64 * 17];
    __shared__ float factor[64];

    const int bx = blockIdx.x;
    const int bh = bx / SPLITB, sp = bx % SPLITB;
    const float k = curvp[bh % HCOUNT];
    const float sk = sqrtf(fabsf(k) + 1e-15f);
    const float maxnorm = (k < 0.0f) ? (1.0f - PROJ_EPS) / sk : 1e15f;
    const int t = threadIdx.x;

    // load context + v2_sum into LDS (padded rows)
    const float* cb = ctxsum + (size_t)bh * CTXSZ;
    #pragma unroll
    for (int i = 0; i < 16; ++i) {
        const int idx = i * 256 + t;
        ctx[(idx >> 6) * LSTR + (idx & 63)] = cb[idx];
    }
    if (t < DHH) v2sum[t] = cb[4096 + t];
    __syncthreads();

    const float* Qb  = Qp  + (size_t)bh * NROWS * DHH;
    float*       Ob  = outp + (size_t)bh * NROWS * DHH;
    const float* dvb = denomWs + (size_t)bh * NROWS;
    const int rloc = t >> 4, c4 = t & 15;
    const int tr = t >> 4, tc = t & 15;

    for (int tile = 0; tile < CHUNKB / 64; ++tile) {
        const int n0 = sp * CHUNKB + tile * 64;
        // ---- stage v1 (64 rows) + per-row Dn ----
        #pragma unroll
        for (int pass = 0; pass < 4; ++pass) {
            const int rl = pass * 16 + rloc;
            const int n = n0 + rl;
            const float4 q4 = *(const float4*)(Qb + (size_t)n * DHH + 4 * c4);
            const float dv = dvb[n];
            const float idv = 1.0f / dv;
            float4 v14;
            v14.x = elu1(q4.x * idv);
            v14.y = elu1(q4.y * idv);
            v14.z = elu1(q4.z * idv);
            v14.w = elu1(q4.w * idv);
            *(float4*)&v1s[rl * LSTR + 4 * c4] = v14;
            const float4 vs = *(const float4*)&v2sum[4 * c4];
            float dn = v14.x * vs.x + v14.y * vs.y + v14.z * vs.z + v14.w * vs.w;
            dn += __shfl_xor(dn, 1);
            dn += __shfl_xor(dn, 2);
            dn += __shfl_xor(dn, 4);
            dn += __shfl_xor(dn, 8);
            if (c4 == 0) {
                const float Dd = (dn == 0.0f) ? EPS_DN : dn;
                dinv[rl] = 1.0f / Dd;
            }
        }
        __syncthreads();
        // ---- register-tiled 64x64 GEMM: X = v1 @ ctx ----
        float acc[4][4] = {{0.f,0.f,0.f,0.f},{0.f,0.f,0.f,0.f},{0.f,0.f,0.f,0.f},{0.f,0.f,0.f,0.f}};
        #pragma unroll 8
        for (int d = 0; d < DHH; ++d) {
            const float4 cv = *(const float4*)&ctx[d * LSTR + 4 * tc];
            const float a0 = v1s[(4 * tr + 0) * LSTR + d];
            const float a1 = v1s[(4 * tr + 1) * LSTR + d];
            const float a2 = v1s[(4 * tr + 2) * LSTR + d];
            const float a3 = v1s[(4 * tr + 3) * LSTR + d];
            acc[0][0] += a0*cv.x; acc[0][1] += a0*cv.y; acc[0][2] += a0*cv.z; acc[0][3] += a0*cv.w;
            acc[1][0] += a1*cv.x; acc[1][1] += a1*cv.y; acc[1][2] += a1*cv.z; acc[1][3] += a1*cv.w;
            acc[2][0] += a2*cv.x; acc[2][1] += a2*cv.y; acc[2][2] += a2*cv.z; acc[2][3] += a2*cv.w;
            acc[3][0] += a3*cv.x; acc[3][1] += a3*cv.y; acc[3][2] += a3*cv.z; acc[3][3] += a3*cv.w;
        }
        // ---- apply D_inv, partial row sumsq ----
        #pragma unroll
        for (int i = 0; i < 4; ++i) {
            const float di = dinv[4 * tr + i];
            acc[i][0] *= di; acc[i][1] *= di; acc[i][2] *= di; acc[i][3] *= di;
            const float ps = acc[i][0]*acc[i][0] + acc[i][1]*acc[i][1]
                           + acc[i][2]*acc[i][2] + acc[i][3]*acc[i][3];
            rowsq[(4 * tr + i) * 17 + tc] = ps;
        }
        __syncthreads();
        // ---- per-row: norm -> project -> mobius(0.5) -> project, folded into one factor ----
        if (t < 64) {
            float s = 0.f;
            #pragma unroll
            for (int q = 0; q < 16; ++q) s += rowsq[t * 17 + q];
            const float norm = fmaxf(sqrtf(s), 1e-15f);
            const float f1 = (norm > maxnorm) ? (maxnorm / norm) : 1.0f;
            const float n2 = norm * f1;
            const float xnorm = fmaxf(n2, 1e-15f);
            const float su = sk * xnorm;
            const float suc = fminf(su, 1.0f - 1e-7f);
            float tk;
            if (k < 0.0f) tk = tanhf(0.5f * atanhf(suc));
            else          tk = tanf(0.5f * atanf(su));
            tk = tk / sk;
            const float f2 = tk / xnorm;
            const float n3 = fmaxf(fabsf(tk), 1e-15f);
            const float f3 = (n3 > maxnorm) ? (maxnorm / n3) : 1.0f;
            factor[t] = f1 * f2 * f3;
        }
        __syncthreads();
        // ---- scale + coalesced float4 store ----
        #pragma unroll
        for (int i = 0; i < 4; ++i) {
            const float f = factor[4 * tr + i];
            float4 o = make_float4(acc[i][0] * f, acc[i][1] * f, acc[i][2] * f, acc[i][3] * f);
            *(float4*)(Ob + (size_t)(n0 + 4 * tr + i) * DHH + 4 * tc) = o;
        }
        __syncthreads();
    }
}

extern "C" void kernel_launch(void* const* d_in, const int* in_sizes, int n_in,
                              void* d_out, int out_size, void* d_ws, size_t ws_size,
                              hipStream_t stream) {
    const float* Q    = (const float*)d_in[0];
    const float* K    = (const float*)d_in[1];
    const float* V    = (const float*)d_in[2];
    const float* mask = (const float*)d_in[3];
    const float* curv = (const float*)d_in[4];
    float* out = (float*)d_out;

    float* denomWs  = (float*)d_ws;                                   // 64*8192 floats
    float* partials = denomWs + (size_t)BHCOUNT * NROWS;              // 64*16*4160 floats
    float* ctxsum   = partials + (size_t)BHCOUNT * SPLITA * CTXSZ;    // 64*4160 floats

    phaseA<<<dim3(BHCOUNT * SPLITA), dim3(256), 0, stream>>>(K, V, mask, curv, denomWs, partials);
    reduceCtx<<<dim3(BHCOUNT), dim3(256), 0, stream>>>(partials, ctxsum);
    phaseB<<<dim3(BHCOUNT * SPLITB), dim3(256), 0, stream>>>(Q, curv, denomWs, ctxsum, out);
}